// Round 3
// baseline (300.590 us; speedup 1.0000x reference)
//
#include <hip/hip_runtime.h>
#include <math.h>

#define R_ 4
#define B_ 16
#define HQ_ 32
#define HKV_ 2
#define G_ 16
#define D_ 128
#define S_ 32
#define L_ 2048
#define P_ 32768
#define TS_ 64
#define KSTR 136   // halves per q_s row: 272B, 16B-aligned rows, odd 4B-banks
#define PSTR 18    // floats per p_s row: even stride -> 8B-aligned float2 reads
#define NEGINF (-INFINITY)

typedef _Float16 h4 __attribute__((ext_vector_type(4)));
typedef _Float16 h8 __attribute__((ext_vector_type(8)));
typedef float    fx4 __attribute__((ext_vector_type(4)));

// ws layout:
//   lse_split [R][B][HKV][S][G]  float   = 65536 f
//   chunk_m   [R][B][HKV][S][G]  float   = 65536 f
//   chunk_acc [R][B][HKV][S][G][D] half  = 8388608 h (16.8 MB)

// One block per (r, b, s) handles BOTH kv heads: shared page table, K rows for
// hkv0/hkv1 are adjacent 512B halves of one 1024B page row, and the PV V-load
// is a single fully-contiguous 1024B wave transaction (lanes 0-31 hkv0,
// lanes 32-63 hkv1).
__global__ __launch_bounds__(256, 8) void fd_stage1(
    const float* __restrict__ q, const float* __restrict__ kc,
    const float* __restrict__ vc, const int* __restrict__ bt,
    const int* __restrict__ lens,
    float* __restrict__ lse_split, float* __restrict__ chunk_m,
    _Float16* __restrict__ chunk_acc)
{
  const int t   = threadIdx.x;
  const int blk = blockIdx.x;          // grid = R_*B_*S_ = 2048
  const int s   = blk & 31;
  const int b   = (blk >> 5) & 15;
  const int r   = blk >> 9;

  const int len = lens[r*B_ + b];
  const int per = (len + 31) >> 5;        // ceil(len/32), 2..64
  const int n0  = s*per;
  const int tn  = min(per, len - n0);     // block-uniform

  const int rb = r*B_ + b;
  // per-hk output bases
  float* lse0 = lse_split + (rb*HKV_ + 0)*(S_*G_) + s*G_;
  float* lse1 = lse_split + (rb*HKV_ + 1)*(S_*G_) + s*G_;
  float* cm0  = chunk_m   + ((rb*HKV_ + 0)*S_ + s)*G_;
  float* cm1  = chunk_m   + ((rb*HKV_ + 1)*S_ + s)*G_;
  _Float16* ca0 = chunk_acc + (size_t)((rb*HKV_ + 0)*S_ + s)*(G_*D_);
  _Float16* ca1 = chunk_acc + (size_t)((rb*HKV_ + 1)*S_ + s)*(G_*D_);

  if (tn <= 0) {                          // empty split: -inf lse/m, zero acc
    if (t < 32) {
      const int hk = t >> 4, g = t & 15;
      (hk ? lse1 : lse0)[g] = NEGINF;
      (hk ? cm1  : cm0 )[g] = NEGINF;
    }
    h8 z = {};
    *(h8*)&ca0[t*8] = z;                  // 256 thr x 8 halves = G_*D_
    *(h8*)&ca1[t*8] = z;
    return;
  }

  __shared__ _Float16 q_s[2][G_][KSTR];               // 8704 B
  __shared__ float    p_s[2][TS_][PSTR];              // 9216 B
  __shared__ int      pg_s[TS_];                      // 256 B
  __shared__ float2   red_s[2][64];                   // 1024 B  (19.2 KB total)

  const int* btb = bt + rb*L_;
  const float* kcb = kc + (size_t)r*(P_*HKV_*D_);
  const float* vcb = vc + (size_t)r*(P_*HKV_*D_);

  // page table slice (n0+63 <= 2047, always in-bounds; tails unused)
  if (t < TS_) pg_s[t] = btb[n0 + t];

  // stage Q (fp32 -> fp16): 32 heads x 128, coalesced
  {
    const float* qb = q + b*HQ_*D_;
    int fi = t;
    #pragma unroll
    for (int i = 0; i < 4; ++i, fi += 256) {
      const int h32 = fi >> 5, dd = (fi & 31)*4;
      const float4 v = *(const float4*)&qb[h32*D_ + dd];
      h4 hv; hv.x=(_Float16)v.x; hv.y=(_Float16)v.y; hv.z=(_Float16)v.z; hv.w=(_Float16)v.w;
      *(h4*)&q_s[h32 >> 4][h32 & 15][dd] = hv;
    }
  }
  __syncthreads();

  // ---- scores via MFMA, both kv heads, K straight from global.
  // Wave w computes D[token 16w..16w+15][head 0..15] for hk0 and hk1.
  // A-row = K token row (lane&15), k = 32c + 8*(lane>>4)+j; rows >= tn masked
  // at load (af=0) -- numerics unchanged, ~20% K traffic saved.
  // C/D: col(head)=lane&15, row(token_local)=4*(lane>>4)+reg.
  const int w  = t >> 6;                  // wave 0..3
  const int l  = t & 63;
  const int hh = l & 15;                  // head / A-row
  const int tq = l >> 4;                  // k-chunk selector
  const bool active = (16*w) < tn;        // wave-uniform

  fx4 d0 = {0.f,0.f,0.f,0.f}, d1 = {0.f,0.f,0.f,0.f};
  if (active) {
    const int row = 16*w + hh;
    const bool rowok = row < tn;
    const int pg = pg_s[row];             // valid address even when !rowok
    const float* kr = kcb + pg*(HKV_*D_) + 8*tq;
    #pragma unroll
    for (int c = 0; c < 4; ++c) {         // K = 4 x 32 = 128
      h8 a0 = {}, a1 = {};
      if (rowok) {
        const float4 f0 = *(const float4*)&kr[c*32];
        const float4 f1 = *(const float4*)&kr[c*32 + 4];
        const float4 f2 = *(const float4*)&kr[D_ + c*32];
        const float4 f3 = *(const float4*)&kr[D_ + c*32 + 4];
        a0[0]=(_Float16)f0.x; a0[1]=(_Float16)f0.y; a0[2]=(_Float16)f0.z; a0[3]=(_Float16)f0.w;
        a0[4]=(_Float16)f1.x; a0[5]=(_Float16)f1.y; a0[6]=(_Float16)f1.z; a0[7]=(_Float16)f1.w;
        a1[0]=(_Float16)f2.x; a1[1]=(_Float16)f2.y; a1[2]=(_Float16)f2.z; a1[3]=(_Float16)f2.w;
        a1[4]=(_Float16)f3.x; a1[5]=(_Float16)f3.y; a1[6]=(_Float16)f3.z; a1[7]=(_Float16)f3.w;
      }
      const h8 b0 = *(const h8*)&q_s[0][hh][c*32 + 8*tq];
      const h8 b1 = *(const h8*)&q_s[1][hh][c*32 + 8*tq];
      d0 = __builtin_amdgcn_mfma_f32_16x16x32_f16(a0, b0, d0, 0, 0, 0);
      d1 = __builtin_amdgcn_mfma_f32_16x16x32_f16(a1, b1, d1, 0, 0, 0);
    }
  }

  const float sc = 0.08838834764831845f;  // 128^-0.5
  const int nb = 16*w + 4*tq;             // this lane's token row base
  float pm0w, ps0w, pm1w, ps1w;
  float e00,e01,e02,e03, e10,e11,e12,e13;
  {
    const float s00 = (nb+0 < tn) ? d0[0]*sc : NEGINF;
    const float s01 = (nb+1 < tn) ? d0[1]*sc : NEGINF;
    const float s02 = (nb+2 < tn) ? d0[2]*sc : NEGINF;
    const float s03 = (nb+3 < tn) ? d0[3]*sc : NEGINF;
    float pm = fmaxf(fmaxf(s00,s01), fmaxf(s02,s03));
    pm = fmaxf(pm, __shfl_xor(pm, 16));
    pm = fmaxf(pm, __shfl_xor(pm, 32));
    const float pms = (pm == NEGINF) ? 0.f : pm;
    e00 = __expf(s00 - pms); e01 = __expf(s01 - pms);
    e02 = __expf(s02 - pms); e03 = __expf(s03 - pms);
    float ps = e00 + e01 + e02 + e03;
    ps += __shfl_xor(ps, 16); ps += __shfl_xor(ps, 32);
    pm0w = pm; ps0w = ps;
  }
  {
    const float s10 = (nb+0 < tn) ? d1[0]*sc : NEGINF;
    const float s11 = (nb+1 < tn) ? d1[1]*sc : NEGINF;
    const float s12 = (nb+2 < tn) ? d1[2]*sc : NEGINF;
    const float s13 = (nb+3 < tn) ? d1[3]*sc : NEGINF;
    float pm = fmaxf(fmaxf(s10,s11), fmaxf(s12,s13));
    pm = fmaxf(pm, __shfl_xor(pm, 16));
    pm = fmaxf(pm, __shfl_xor(pm, 32));
    const float pms = (pm == NEGINF) ? 0.f : pm;
    e10 = __expf(s10 - pms); e11 = __expf(s11 - pms);
    e12 = __expf(s12 - pms); e13 = __expf(s13 - pms);
    float ps = e10 + e11 + e12 + e13;
    ps += __shfl_xor(ps, 16); ps += __shfl_xor(ps, 32);
    pm1w = pm; ps1w = ps;
  }

  if (l < 16) {
    red_s[0][w*16 + l] = make_float2(pm0w, ps0w);
    red_s[1][w*16 + l] = make_float2(pm1w, ps1w);
  }
  __syncthreads();

  // cross-wave combine per hk: pm = split max, ps = sum exp(s - pm)
  float pm0, pm1;
  {
    const float2 a = red_s[0][hh], c2 = red_s[0][16+hh];
    const float2 e2 = red_s[0][32+hh], g2r = red_s[0][48+hh];
    pm0 = fmaxf(fmaxf(a.x,c2.x), fmaxf(e2.x,g2r.x));
    const float ps = a.y*__expf(a.x-pm0) + c2.y*__expf(c2.x-pm0)
                   + e2.y*__expf(e2.x-pm0) + g2r.y*__expf(g2r.x-pm0);
    if (w == 0 && l < 16) { lse0[l] = pm0 + __logf(ps); cm0[l] = pm0; }
  }
  {
    const float2 a = red_s[1][hh], c2 = red_s[1][16+hh];
    const float2 e2 = red_s[1][32+hh], g2r = red_s[1][48+hh];
    pm1 = fmaxf(fmaxf(a.x,c2.x), fmaxf(e2.x,g2r.x));
    const float ps = a.y*__expf(a.x-pm1) + c2.y*__expf(c2.x-pm1)
                   + e2.y*__expf(e2.x-pm1) + g2r.y*__expf(g2r.x-pm1);
    if (w == 1 && l < 16) { lse1[l] = pm1 + __logf(ps); cm1[l] = pm1; }
  }

  // p transposed: p_s[hk][n][h] = exp(s - pm); invalid rows write zeros
  if (active) {
    const float c0 = __expf(pm0w - pm0);   // pm0w=-inf -> 0
    const float c1 = __expf(pm1w - pm1);
    p_s[0][nb+0][hh] = e00*c0; p_s[0][nb+1][hh] = e01*c0;
    p_s[0][nb+2][hh] = e02*c0; p_s[0][nb+3][hh] = e03*c0;
    p_s[1][nb+0][hh] = e10*c1; p_s[1][nb+1][hh] = e11*c1;
    p_s[1][nb+2][hh] = e12*c1; p_s[1][nb+3][hh] = e13*c1;
  }
  __syncthreads();

  // PV: wave w owns heads 4w..4w+3; lanes 0-31 -> hkv0, lanes 32-63 -> hkv1;
  // V wave-load = contiguous 1024B (full page row, both kv heads).
  const int hk = (t >> 5) & 1;            // = (l>>5)
  const int d4 = (t & 31)*4;
  const float* vb = vcb + hk*D_ + d4;
  const float* pp = &p_s[hk][0][4*w];
  float4 a0 = make_float4(0,0,0,0), a1 = make_float4(0,0,0,0);
  float4 a2 = make_float4(0,0,0,0), a3 = make_float4(0,0,0,0);
  #pragma unroll 2
  for (int n = 0; n < tn; ++n) {
    const int pg = pg_s[n];               // LDS broadcast
    const float4 v4 = *(const float4*)&vb[pg*(HKV_*D_)];
    const float2 p01 = *(const float2*)&pp[n*PSTR];
    const float2 p23 = *(const float2*)&pp[n*PSTR + 2];
    a0.x += p01.x*v4.x; a0.y += p01.x*v4.y; a0.z += p01.x*v4.z; a0.w += p01.x*v4.w;
    a1.x += p01.y*v4.x; a1.y += p01.y*v4.y; a1.z += p01.y*v4.z; a1.w += p01.y*v4.w;
    a2.x += p23.x*v4.x; a2.y += p23.x*v4.y; a2.z += p23.x*v4.z; a2.w += p23.x*v4.w;
    a3.x += p23.y*v4.x; a3.y += p23.y*v4.y; a3.z += p23.y*v4.z; a3.w += p23.y*v4.w;
  }

  _Float16* ca = hk ? ca1 : ca0;
  h4 o;
  o.x=(_Float16)a0.x; o.y=(_Float16)a0.y; o.z=(_Float16)a0.z; o.w=(_Float16)a0.w;
  *(h4*)&ca[(4*w+0)*D_ + d4] = o;
  o.x=(_Float16)a1.x; o.y=(_Float16)a1.y; o.z=(_Float16)a1.z; o.w=(_Float16)a1.w;
  *(h4*)&ca[(4*w+1)*D_ + d4] = o;
  o.x=(_Float16)a2.x; o.y=(_Float16)a2.y; o.z=(_Float16)a2.z; o.w=(_Float16)a2.w;
  *(h4*)&ca[(4*w+2)*D_ + d4] = o;
  o.x=(_Float16)a3.x; o.y=(_Float16)a3.y; o.z=(_Float16)a3.z; o.w=(_Float16)a3.w;
  *(h4*)&ca[(4*w+3)*D_ + d4] = o;
}

__global__ __launch_bounds__(128) void fd_stage2(
    const float* __restrict__ lse_split, const float* __restrict__ chunk_m,
    const _Float16* __restrict__ chunk_acc, float* __restrict__ out)
{
  const int bh  = blockIdx.x;          // b*32 + h
  const int b   = bh >> 5, h = bh & 31;
  const int hkv = h >> 4, g = h & 15;
  const int d   = threadIdx.x;

  float m_r[R_], lse_r[R_];
  #pragma unroll
  for (int r = 0; r < R_; ++r) {
    const float* ls = lse_split + ((r*B_ + b)*HKV_ + hkv)*(S_*G_) + g;
    float m = NEGINF;
    #pragma unroll 8
    for (int s2 = 0; s2 < S_; ++s2) m = fmaxf(m, ls[s2*G_]);
    float sum = 0.f;
    #pragma unroll 8
    for (int s2 = 0; s2 < S_; ++s2) sum += __expf(ls[s2*G_] - m);
    m_r[r]   = m;
    lse_r[r] = m + __logf(sum);
  }
  const float M = fmaxf(fmaxf(lse_r[0], lse_r[1]), fmaxf(lse_r[2], lse_r[3]));
  float denom = 0.f, o = 0.f;
  #pragma unroll
  for (int r = 0; r < R_; ++r) {
    const float w = __expf(lse_r[r] - M);
    denom += w;
    const float* cm = chunk_m + (((r*B_ + b)*HKV_ + hkv)*S_)*G_ + g;
    const _Float16* ca = chunk_acc
        + (size_t)(((r*B_ + b)*HKV_ + hkv)*S_)*(G_*D_) + g*D_ + d;
    float a = 0.f;
    #pragma unroll 8
    for (int c = 0; c < S_; ++c)
      a += __expf(cm[c*G_] - m_r[r]) * (float)ca[(size_t)c*(G_*D_)];
    o += w * a;   // faithful: acc_r UNNORMALIZED, weighted by exp(lse_r - M)
  }
  out[(size_t)bh*D_ + d] = o / denom;
}

extern "C" void kernel_launch(void* const* d_in, const int* in_sizes, int n_in,
                              void* d_out, int out_size, void* d_ws, size_t ws_size,
                              hipStream_t stream) {
  const float* q   = (const float*)d_in[0];
  const float* kc  = (const float*)d_in[1];
  const float* vc  = (const float*)d_in[2];
  const int*   bt  = (const int*)d_in[3];
  const int*   len = (const int*)d_in[4];
  float* out = (float*)d_out;
  float* ws  = (float*)d_ws;

  const size_t lse_f = (size_t)R_*B_*HKV_*S_*G_;   // 65536
  float*    lse_split = ws;
  float*    chunk_m   = ws + lse_f;
  _Float16* chunk_acc = (_Float16*)(ws + 2*lse_f);

  fd_stage1<<<dim3(R_*B_*S_), dim3(256), 0, stream>>>(
      q, kc, vc, bt, len, lse_split, chunk_m, chunk_acc);
  fd_stage2<<<dim3(B_*HQ_), dim3(128), 0, stream>>>(
      lse_split, chunk_m, chunk_acc, out);
}